// Round 12
// baseline (184.876 us; speedup 1.0000x reference)
//
#include <hip/hip_runtime.h>

// CascadeImageGuideUpsample, R11:
//  conv v3: one block = one 4x64 output tile = ALL 4 parities (R10 spread
//  parities across blocks -> same feat patch fetched on 4 XCDs; 22MB FETCH).
//  Block stages the shared feat patch (4x34 x 32ic) + hf patch (6x66 x 3ch)
//  into 23.3KB LDS once; wave = parity (weights wave-uniform -> s_load),
//  thread = one output pixel, full K in registers, softmax + 25->9 CARAFE
//  fold in-thread. No K-split reduce, no 53KB red[], 1 barrier, no idle waves.

// ---- repack both weight sets: W2[((p*32+ic)*4+src)*25+oc], wTh[(tap*3+h)*25+oc]
__global__ __launch_bounds__(256) void repack_kernel(
    const float* __restrict__ w0s, const float* __restrict__ w1s,
    float* __restrict__ W2a, float* __restrict__ wTha,
    float* __restrict__ W2b, float* __restrict__ wThb) {
  int i = blockIdx.x * 256 + threadIdx.x;
  const float* w; float* W2; float* wTh; int k = i;
  if (i < 13475) { w = w0s; W2 = W2a; wTh = wTha; }
  else { k = i - 13475; if (k >= 13475) return; w = w1s; W2 = W2b; wTh = wThb; }
  if (k < 12800) {
    int oc = k % 25; int j = k / 25;
    int src = j & 3; j >>= 2;
    int ic = j & 31; int p = j >> 5;       // parity 0..3 = (py*2+px)
    int py = p >> 1, px = p & 1;
    int a = src >> 1, b = src & 1;
    float s = 0.f;
    for (int ky = 0; ky < 3; ++ky) {
      int rs = (py == 0) ? (ky >= 1) : (ky >= 2);
      if (rs != a) continue;
      for (int kx = 0; kx < 3; ++kx) {
        int cs = (px == 0) ? (kx >= 1) : (kx >= 2);
        if (cs != b) continue;
        s += w[oc * 315 + ic * 9 + ky * 3 + kx];
      }
    }
    W2[k] = s;
  } else {
    int kk = k - 12800;
    int oc = kk % 25; int j = kk / 25;
    int h = j % 3; int tap = j / 3;
    wTh[kk] = w[oc * 315 + (32 + h) * 9 + tap];
  }
}

// ---- down2: out[c,y,x] = avg of 2x2. out [3,192,192], in [3,384,384]
__global__ __launch_bounds__(256) void down2_kernel(
    const float* __restrict__ in, float* __restrict__ out) {
  int idx = blockIdx.x * 256 + threadIdx.x;
  if (idx >= 3 * 192 * 192) return;
  int x = idx % 192; int t = idx / 192; int y = t % 192; int c = t / 192;
  const float* p = in + (c * 384 + 2 * y) * 384 + 2 * x;
  out[idx] = 0.25f * (p[0] + p[1] + p[384] + p[385]);
}

// ---- hf0: out = 2*I192 - up2(down2(I192)), I96 taps computed on the fly.
__global__ __launch_bounds__(256) void hf0_kernel(
    const float* __restrict__ I192, float* __restrict__ out) {
  int idx = blockIdx.x * 256 + threadIdx.x;
  if (idx >= 3 * 192 * 192) return;
  int x = idx % 192; int t = idx / 192; int y = t % 192; int c = t / 192;
  int m = y >> 1; int ya, yb; float wya, wyb;
  if ((y & 1) == 0) { ya = m - 1 < 0 ? 0 : m - 1; yb = m; wya = 0.25f; wyb = 0.75f; }
  else             { ya = m; yb = m + 1 > 95 ? 95 : m + 1; wya = 0.75f; wyb = 0.25f; }
  int n = x >> 1; int xa, xb; float wxa, wxb;
  if ((x & 1) == 0) { xa = n - 1 < 0 ? 0 : n - 1; xb = n; wxa = 0.25f; wxb = 0.75f; }
  else             { xa = n; xb = n + 1 > 95 ? 95 : n + 1; wxa = 0.75f; wxb = 0.25f; }
  const float* base = I192 + c * 192 * 192;
  auto I96v = [&](int mm, int nn) {
    const float* p = base + (2 * mm) * 192 + 2 * nn;
    return 0.25f * (p[0] + p[1] + p[192] + p[193]);
  };
  float up = wya * (wxa * I96v(ya, xa) + wxb * I96v(ya, xb))
           + wyb * (wxa * I96v(yb, xa) + wxb * I96v(yb, xb));
  out[idx] = 2.0f * base[y * 192 + x] - up;
}

// ---- highboost (iter-1): out = 2*img - up2(I192). base [3,384,384], lr [3,192,192]
__global__ __launch_bounds__(256) void highboost_kernel(
    const float* __restrict__ base, const float* __restrict__ lr,
    float* __restrict__ out) {
  const int H = 192, OW = 384;
  int idx = blockIdx.x * 256 + threadIdx.x;
  if (idx >= 3 * 384 * 384) return;
  int x = idx % OW; int t = idx / OW; int y = t % 384; int c = t / 384;
  int m = y >> 1; int ya, yb; float wya, wyb;
  if ((y & 1) == 0) { ya = m - 1 < 0 ? 0 : m - 1; yb = m; wya = 0.25f; wyb = 0.75f; }
  else             { ya = m; yb = m + 1 >= H ? H - 1 : m + 1; wya = 0.75f; wyb = 0.25f; }
  int n = x >> 1; int xa, xb; float wxa, wxb;
  if ((x & 1) == 0) { xa = n - 1 < 0 ? 0 : n - 1; xb = n; wxa = 0.25f; wxb = 0.75f; }
  else             { xa = n; xb = n + 1 >= H ? H - 1 : n + 1; wxa = 0.75f; wxb = 0.25f; }
  const float* p = lr + c * H * H;
  float up = wya * (wxa * p[ya * H + xa] + wxb * p[ya * H + xb])
           + wyb * (wxa * p[yb * H + xa] + wxb * p[yb * H + xb]);
  out[idx] = 2.0f * base[idx] - up;
}

// ---- conv v3: block = 4x64 output tile (source tile 2 rows x 32 cols).
// Grid: (Hf/2)*(Wf/32) blocks (x-major), 256 thr = 4 waves; wave = parity.
__global__ __launch_bounds__(256, 4) void conv_softmax_kernel(
    const float* __restrict__ feat, const float* __restrict__ hf,
    const float* __restrict__ W2, const float* __restrict__ wTh,
    const float* __restrict__ b, float* __restrict__ CW,
    int Hf, int Wf) {
  const int OH = 2 * Hf, OW = 2 * Wf, Np = OH * OW, fp = Hf * Wf;
  __shared__ float sf[32 * 144];   // [ic][r<4 *36][c<34]
  __shared__ float sh[3 * 408];    // [ch][R<6 *68][C<66]
  const int t = threadIdx.x;
  const int TW = Wf >> 5;
  // XCD-chunked swizzle (gridDim.x % 8 == 0 for both iterations)
  const int wg = ((blockIdx.x & 7) * (gridDim.x >> 3)) + (blockIdx.x >> 3);
  const int tx = wg % TW, ty = wg / TW;
  const int gx0 = tx << 5, gy0 = ty << 1;

  // stage feat patch: rows gy0-1..gy0+2, cols gx0-1..gx0+32 (zero OOB = exact pad)
  for (int i = t; i < 32 * 136; i += 256) {
    int ic = i / 136, rem = i - ic * 136;
    int r = rem / 34, c = rem - r * 34;
    int gr = gy0 - 1 + r, gc = gx0 - 1 + c;
    float v = 0.f;
    if ((unsigned)gr < (unsigned)Hf && (unsigned)gc < (unsigned)Wf)
      v = feat[ic * fp + gr * Wf + gc];
    sf[ic * 144 + r * 36 + c] = v;
  }
  // stage hf patch: rows 2*gy0-1..2*gy0+4, cols 2*gx0-1..2*gx0+64
  for (int i = t; i < 3 * 396; i += 256) {
    int ch = i / 396, rem = i - ch * 396;
    int R = rem / 66, C = rem - R * 66;
    int gr = 2 * gy0 - 1 + R, gc = 2 * gx0 - 1 + C;
    float v = 0.f;
    if ((unsigned)gr < (unsigned)OH && (unsigned)gc < (unsigned)OW)
      v = hf[ch * Np + gr * OW + gc];
    sh[ch * 408 + R * 68 + C] = v;
  }
  __syncthreads();

  const int w = __builtin_amdgcn_readfirstlane(t >> 6);  // wave = parity
  const int lane = t & 63;
  const int py = w >> 1, px = w & 1;
  const int ly = lane >> 5, lx = lane & 31;
  const int lr0 = ly + py;          // local feat row of source r0
  const int lc0 = lx + px;          // local feat col of source c0

  float acc[25];
#pragma unroll
  for (int oc = 0; oc < 25; ++oc) acc[oc] = b[oc];       // uniform s_load

  for (int ic = 0; ic < 32; ++ic) {
    const float* base = sf + ic * 144 + lr0 * 36 + lc0;
    float v00 = base[0], v01 = base[1], v10 = base[36], v11 = base[37];
    const float* wp = W2 + (size_t)((w * 32 + ic) * 4) * 25;  // uniform s_load
#pragma unroll
    for (int oc = 0; oc < 25; ++oc)
      acc[oc] += v00 * wp[oc] + v01 * wp[25 + oc] + v10 * wp[50 + oc] + v11 * wp[75 + oc];
  }
  {  // hf channels, per-tap
    const int R0 = 2 * ly + py, C0 = 2 * lx + px;
#pragma unroll
    for (int ky = 0; ky < 3; ++ky)
#pragma unroll
      for (int kx = 0; kx < 3; ++kx)
#pragma unroll
        for (int ch = 0; ch < 3; ++ch) {
          float v = sh[ch * 408 + (R0 + ky) * 68 + (C0 + kx)];
          const float* wp = wTh + ((ky * 3 + kx) * 3 + ch) * 25;  // uniform s_load
#pragma unroll
          for (int oc = 0; oc < 25; ++oc) acc[oc] = fmaf(v, wp[oc], acc[oc]);
        }
  }

  // per-thread softmax + 25->9 fold (static map per parity) + CW store
  const int y = 2 * (gy0 + ly) + py, x = 2 * (gx0 + lx) + px;
  float mx = acc[0];
#pragma unroll
  for (int oc = 1; oc < 25; ++oc) mx = fmaxf(mx, acc[oc]);
  float ssum = 0.f;
#pragma unroll
  for (int oc = 0; oc < 25; ++oc) { acc[oc] = __expf(acc[oc] - mx); ssum += acc[oc]; }
  float inv = 1.0f / ssum;

  bool vy[5], vx[5];
#pragma unroll
  for (int d = 0; d < 5; ++d) {
    vy[d] = (unsigned)(y + d - 2) < (unsigned)OH;
    vx[d] = (unsigned)(x + d - 2) < (unsigned)OW;
  }
  float rs[3][5];
  if (py == 0) {       // wave-uniform branch
#pragma unroll
    for (int dj = 0; dj < 5; ++dj) {
      float m0 = (vy[0] && vx[dj]) ? acc[0 + dj] : 0.f;
      float m1 = (vy[1] && vx[dj]) ? acc[5 + dj] : 0.f;
      float m2 = (vy[2] && vx[dj]) ? acc[10 + dj] : 0.f;
      float m3 = (vy[3] && vx[dj]) ? acc[15 + dj] : 0.f;
      float m4 = (vy[4] && vx[dj]) ? acc[20 + dj] : 0.f;
      rs[0][dj] = m0 + m1; rs[1][dj] = m2 + m3; rs[2][dj] = m4;
    }
  } else {
#pragma unroll
    for (int dj = 0; dj < 5; ++dj) {
      float m0 = (vy[0] && vx[dj]) ? acc[0 + dj] : 0.f;
      float m1 = (vy[1] && vx[dj]) ? acc[5 + dj] : 0.f;
      float m2 = (vy[2] && vx[dj]) ? acc[10 + dj] : 0.f;
      float m3 = (vy[3] && vx[dj]) ? acc[15 + dj] : 0.f;
      float m4 = (vy[4] && vx[dj]) ? acc[20 + dj] : 0.f;
      rs[0][dj] = m0; rs[1][dj] = m1 + m2; rs[2][dj] = m3 + m4;
    }
  }
  float cw[9];
#pragma unroll
  for (int r = 0; r < 3; ++r) {
    if (px == 0) {
      cw[r * 3 + 0] = rs[r][0] + rs[r][1];
      cw[r * 3 + 1] = rs[r][2] + rs[r][3];
      cw[r * 3 + 2] = rs[r][4];
    } else {
      cw[r * 3 + 0] = rs[r][0];
      cw[r * 3 + 1] = rs[r][1] + rs[r][2];
      cw[r * 3 + 2] = rs[r][3] + rs[r][4];
    }
  }
  const int pix = y * OW + x;
#pragma unroll
  for (int tap = 0; tap < 9; ++tap) CW[tap * Np + pix] = cw[tap] * inv;
}

// ---- CARAFE applying precomputed folded weights. Channel-chunked by gridDim.y.
__global__ __launch_bounds__(256) void carafe_kernel(
    const float* __restrict__ CW,
    const float* __restrict__ in0, float* __restrict__ out0, int C0,
    const float* __restrict__ in1, float* __restrict__ out1, int C1,
    int CS, int Hf, int Wf) {
  const int OW = 2 * Wf;
  const int Np = 4 * Hf * Wf;
  int pix = blockIdx.x * 256 + threadIdx.x;
  if (pix >= Np) return;
  int x = pix % OW, y = pix / OW;
  int ry0 = (y >> 1) - 1, rx0 = (x >> 1) - 1;
  int sy[3], sx[3];
#pragma unroll
  for (int i = 0; i < 3; ++i) {     // clamp; OOB rows/cols have cw==0
    int v = ry0 + i; sy[i] = v < 0 ? 0 : (v >= Hf ? Hf - 1 : v);
    int u = rx0 + i; sx[i] = u < 0 ? 0 : (u >= Wf ? Wf - 1 : u);
  }
  float cw[9];
#pragma unroll
  for (int i = 0; i < 9; ++i) cw[i] = CW[i * Np + pix];
  const int fplane = Hf * Wf;
  int cbeg = blockIdx.y * CS;
  int cend = cbeg + CS; int Ct = C0 + C1; if (cend > Ct) cend = Ct;
  for (int c = cbeg; c < cend; ++c) {
    const float* p; float* q;
    if (c < C0) { p = in0 + c * fplane; q = out0 + c * Np; }
    else        { p = in1 + (c - C0) * fplane; q = out1 + (c - C0) * Np; }
    const float* r0 = p + sy[0] * Wf;
    const float* r1 = p + sy[1] * Wf;
    const float* r2 = p + sy[2] * Wf;
    float acc = cw[0] * r0[sx[0]] + cw[1] * r0[sx[1]] + cw[2] * r0[sx[2]]
              + cw[3] * r1[sx[0]] + cw[4] * r1[sx[1]] + cw[5] * r1[sx[2]]
              + cw[6] * r2[sx[0]] + cw[7] * r2[sx[1]] + cw[8] * r2[sx[2]];
    q[pix] = acc;
  }
}

extern "C" void kernel_launch(void* const* d_in, const int* in_sizes, int n_in,
                              void* d_out, int out_size, void* d_ws, size_t ws_size,
                              hipStream_t stream) {
  (void)in_sizes; (void)n_in; (void)out_size; (void)ws_size;
  const float* feat = (const float*)d_in[0];  // [1,32,96,96]
  const float* seg  = (const float*)d_in[1];  // [1,19,96,96]
  const float* img  = (const float*)d_in[2];  // [1,3,384,384]
  const float* w0   = (const float*)d_in[3];  // [25,35,3,3]
  const float* b0   = (const float*)d_in[4];  // [25]
  const float* w1   = (const float*)d_in[5];
  const float* b1   = (const float*)d_in[6];
  float* out = (float*)d_out;                 // [1,19,384,384]

  float* ws   = (float*)d_ws;
  float* I192 = ws;                    // 3*192*192
  float* HF   = I192 + 3 * 192 * 192;  // 3*384*384 max
  float* CWb  = HF   + 3 * 384 * 384;  // 9*384*384 max
  float* F1   = CWb  + 9 * 384 * 384;  // 32*192*192
  float* S1   = F1   + 32 * 192 * 192; // 19*192*192
  float* W2_0 = S1   + 19 * 192 * 192; // 12800
  float* WTH0 = W2_0 + 12800;          // 675
  float* W2_1 = WTH0 + 675;            // 12800
  float* WTH1 = W2_1 + 12800;          // 675

  repack_kernel<<<106, 256, 0, stream>>>(w0, w1, W2_0, WTH0, W2_1, WTH1);
  down2_kernel<<<432, 256, 0, stream>>>(img, I192);

  // ---- iteration 0 (Hf=96) ----
  hf0_kernel<<<432, 256, 0, stream>>>(I192, HF);
  conv_softmax_kernel<<<48 * 3, 256, 0, stream>>>(
      feat, HF, W2_0, WTH0, b0, CWb, 96, 96);
  carafe_kernel<<<dim3(144, 3), 256, 0, stream>>>(
      CWb, seg, S1, 19, feat, F1, 32, 17, 96, 96);

  // ---- iteration 1 (Hf=192) ----
  highboost_kernel<<<1728, 256, 0, stream>>>(img, I192, HF);
  conv_softmax_kernel<<<96 * 6, 256, 0, stream>>>(
      F1, HF, W2_1, WTH1, b1, CWb, 192, 192);
  carafe_kernel<<<dim3(576, 2), 256, 0, stream>>>(
      CWb, S1, out, 19, nullptr, nullptr, 0, 10, 192, 192);
}

// Round 14
// 163.592 us; speedup vs baseline: 1.1301x; 1.1301x over previous
//
#include <hip/hip_runtime.h>

// CascadeImageGuideUpsample, R13: 3 launches (was 8; ~10us/launch overhead
// dominated). prep = repack + HF0-from-img. fused<M> = conv3x3 + softmax +
// 25->9 fold + CARAFE from the SAME staged LDS patches (patch rows gy0-1..
// gy0+2 == carafe's 3x3 source window; OOB-zero slots safe since fold
// guarantees cw==0 there). Iter-1 inlines HF1+I192 from img during staging;
// carafe1 covers only the 19 returned seg channels.

// ---- prep: blocks 0..105 repack both weight sets; blocks 106..537 HF0.
// W2[((p*32+ic)*4+src)*25+oc], wTh[(tap*3+h)*25+oc]; w is [25,35,3,3].
// HF0[c,y,x] (192-res) = 2*down2(img) - up2(down2(down2(img))), all inline.
__global__ __launch_bounds__(256) void prep_kernel(
    const float* __restrict__ w0s, const float* __restrict__ w1s,
    const float* __restrict__ img,
    float* __restrict__ W2a, float* __restrict__ wTha,
    float* __restrict__ W2b, float* __restrict__ wThb,
    float* __restrict__ HF0) {
  if (blockIdx.x < 106) {
    int i = blockIdx.x * 256 + threadIdx.x;
    const float* w; float* W2; float* wTh; int k = i;
    if (i < 13475) { w = w0s; W2 = W2a; wTh = wTha; }
    else { k = i - 13475; if (k >= 13475) return; w = w1s; W2 = W2b; wTh = wThb; }
    if (k < 12800) {
      int oc = k % 25; int j = k / 25;
      int src = j & 3; j >>= 2;
      int ic = j & 31; int p = j >> 5;       // parity = py*2+px
      int py = p >> 1, px = p & 1;
      int a = src >> 1, b = src & 1;
      float s = 0.f;
      for (int ky = 0; ky < 3; ++ky) {
        int rs = (py == 0) ? (ky >= 1) : (ky >= 2);
        if (rs != a) continue;
        for (int kx = 0; kx < 3; ++kx) {
          int cs = (px == 0) ? (kx >= 1) : (kx >= 2);
          if (cs != b) continue;
          s += w[oc * 315 + ic * 9 + ky * 3 + kx];
        }
      }
      W2[k] = s;
    } else {
      int kk = k - 12800;
      int oc = kk % 25; int j = kk / 25;
      int h = j % 3; int tap = j / 3;
      wTh[kk] = w[oc * 315 + (32 + h) * 9 + tap];
    }
    return;
  }
  int idx = (blockIdx.x - 106) * 256 + threadIdx.x;
  if (idx >= 3 * 192 * 192) return;
  int x = idx % 192; int t2 = idx / 192; int y = t2 % 192; int c = t2 / 192;
  const float* ip = img + c * 147456;
  int m = y >> 1; int ya, yb; float wya, wyb;
  if ((y & 1) == 0) { ya = m - 1 < 0 ? 0 : m - 1; yb = m; wya = 0.25f; wyb = 0.75f; }
  else             { ya = m; yb = m + 1 > 95 ? 95 : m + 1; wya = 0.75f; wyb = 0.25f; }
  int n = x >> 1; int xa, xb; float wxa, wxb;
  if ((x & 1) == 0) { xa = n - 1 < 0 ? 0 : n - 1; xb = n; wxa = 0.25f; wxb = 0.75f; }
  else             { xa = n; xb = n + 1 > 95 ? 95 : n + 1; wxa = 0.75f; wxb = 0.25f; }
  auto I96v = [&](int mm, int nn) {
    const float* p = ip + (4 * mm) * 384 + 4 * nn;
    float s = 0.f;
#pragma unroll
    for (int i = 0; i < 4; ++i) s += p[i * 384] + p[i * 384 + 1] + p[i * 384 + 2] + p[i * 384 + 3];
    return s * 0.0625f;
  };
  const float* q = ip + (2 * y) * 384 + 2 * x;
  float i192 = 0.25f * (q[0] + q[1] + q[384] + q[385]);
  float up = wya * (wxa * I96v(ya, xa) + wxb * I96v(ya, xb))
           + wyb * (wxa * I96v(yb, xa) + wxb * I96v(yb, xb));
  HF0[idx] = 2.0f * i192 - up;
}

// ---- fused conv+softmax+fold+carafe. Block = 4x64 output tile (all parities).
// MODE 0: Hf=96, hf staged from HF0 buffer, carafe -> outS(19)+outF(32).
// MODE 1: Hf=192, hf computed inline (2*img - up2(I192-from-img)), carafe -> outS only.
template <int MODE>
__global__ __launch_bounds__(256) void fused_kernel(
    const float* __restrict__ feat, const float* __restrict__ seg,
    const float* __restrict__ img, const float* __restrict__ HF0,
    const float* __restrict__ W2, const float* __restrict__ wTh,
    const float* __restrict__ b,
    float* __restrict__ outF, float* __restrict__ outS,
    int Hf, int Wf) {
  const int OH = 2 * Hf, OW = 2 * Wf, Np = OH * OW, fp = Hf * Wf;
  __shared__ float sf[32 * 144];   // feat patch [ic][r<4 *36][c<34]
  __shared__ float ss[19 * 144];   // seg patch
  __shared__ float sh[3 * 408];    // hf patch  [ch][R<6 *68][C<66]
  const int t = threadIdx.x;
  const int TW = Wf >> 5;
  const int wg = ((blockIdx.x & 7) * (gridDim.x >> 3)) + (blockIdx.x >> 3);
  const int tx = wg % TW, ty = wg / TW;
  const int gx0 = tx << 5, gy0 = ty << 1;

  for (int i = t; i < 32 * 136; i += 256) {      // feat: zero OOB = exact pad
    int ic = i / 136, rem = i - ic * 136;
    int r = rem / 34, c = rem - r * 34;
    int gr = gy0 - 1 + r, gc = gx0 - 1 + c;
    float v = 0.f;
    if ((unsigned)gr < (unsigned)Hf && (unsigned)gc < (unsigned)Wf)
      v = feat[ic * fp + gr * Wf + gc];
    sf[ic * 144 + r * 36 + c] = v;
  }
  for (int i = t; i < 19 * 136; i += 256) {      // seg patch (carafe source)
    int sc = i / 136, rem = i - sc * 136;
    int r = rem / 34, c = rem - r * 34;
    int gr = gy0 - 1 + r, gc = gx0 - 1 + c;
    float v = 0.f;
    if ((unsigned)gr < (unsigned)Hf && (unsigned)gc < (unsigned)Wf)
      v = seg[sc * fp + gr * Wf + gc];
    ss[sc * 144 + r * 36 + c] = v;
  }
  for (int i = t; i < 3 * 396; i += 256) {       // hf patch
    int ch = i / 396, rem = i - ch * 396;
    int R = rem / 66, C = rem - R * 66;
    int gr = 2 * gy0 - 1 + R, gc = 2 * gx0 - 1 + C;
    float v = 0.f;
    if ((unsigned)gr < (unsigned)OH && (unsigned)gc < (unsigned)OW) {
      if (MODE == 0) {
        v = HF0[ch * 36864 + gr * 192 + gc];
      } else {
        const float* ip = img + ch * 147456;
        int m = gr >> 1; int ya, yb; float wya, wyb;
        if ((gr & 1) == 0) { ya = m - 1 < 0 ? 0 : m - 1; yb = m; wya = 0.25f; wyb = 0.75f; }
        else               { ya = m; yb = m + 1 > 191 ? 191 : m + 1; wya = 0.75f; wyb = 0.25f; }
        int n = gc >> 1; int xa, xb; float wxa, wxb;
        if ((gc & 1) == 0) { xa = n - 1 < 0 ? 0 : n - 1; xb = n; wxa = 0.25f; wxb = 0.75f; }
        else               { xa = n; xb = n + 1 > 191 ? 191 : n + 1; wxa = 0.75f; wxb = 0.25f; }
        auto I192v = [&](int mm, int nn) {
          const float* p = ip + (2 * mm) * 384 + 2 * nn;
          return 0.25f * (p[0] + p[1] + p[384] + p[385]);
        };
        float up = wya * (wxa * I192v(ya, xa) + wxb * I192v(ya, xb))
                 + wyb * (wxa * I192v(yb, xa) + wxb * I192v(yb, xb));
        v = 2.0f * ip[gr * 384 + gc] - up;
      }
    }
    sh[ch * 408 + R * 68 + C] = v;
  }
  __syncthreads();

  const int w = __builtin_amdgcn_readfirstlane(t >> 6);  // wave = parity
  const int lane = t & 63;
  const int py = w >> 1, px = w & 1;
  const int ly = lane >> 5, lx = lane & 31;
  const int lr0 = ly + py, lc0 = lx + px;

  float acc[25];
#pragma unroll
  for (int oc = 0; oc < 25; ++oc) acc[oc] = b[oc];       // uniform s_load

  for (int ic = 0; ic < 32; ++ic) {
    const float* base = sf + ic * 144 + lr0 * 36 + lc0;
    float v00 = base[0], v01 = base[1], v10 = base[36], v11 = base[37];
    const float* wp = W2 + (size_t)((w * 32 + ic) * 4) * 25;  // uniform s_load
#pragma unroll
    for (int oc = 0; oc < 25; ++oc)
      acc[oc] += v00 * wp[oc] + v01 * wp[25 + oc] + v10 * wp[50 + oc] + v11 * wp[75 + oc];
  }
  {
    const int R0 = 2 * ly + py, C0 = 2 * lx + px;
#pragma unroll
    for (int ky = 0; ky < 3; ++ky)
#pragma unroll
      for (int kx = 0; kx < 3; ++kx)
#pragma unroll
        for (int ch = 0; ch < 3; ++ch) {
          float v = sh[ch * 408 + (R0 + ky) * 68 + (C0 + kx)];
          const float* wp = wTh + ((ky * 3 + kx) * 3 + ch) * 25;
#pragma unroll
          for (int oc = 0; oc < 25; ++oc) acc[oc] = fmaf(v, wp[oc], acc[oc]);
        }
  }

  // softmax + 25->9 fold (static per parity) -> normalized cw[9]
  const int y = 2 * (gy0 + ly) + py, x = 2 * (gx0 + lx) + px;
  float mx = acc[0];
#pragma unroll
  for (int oc = 1; oc < 25; ++oc) mx = fmaxf(mx, acc[oc]);
  float ssum = 0.f;
#pragma unroll
  for (int oc = 0; oc < 25; ++oc) { acc[oc] = __expf(acc[oc] - mx); ssum += acc[oc]; }
  float inv = 1.0f / ssum;

  bool vy[5], vx[5];
#pragma unroll
  for (int d = 0; d < 5; ++d) {
    vy[d] = (unsigned)(y + d - 2) < (unsigned)OH;
    vx[d] = (unsigned)(x + d - 2) < (unsigned)OW;
  }
  float rs[3][5];
  if (py == 0) {       // wave-uniform branch
#pragma unroll
    for (int dj = 0; dj < 5; ++dj) {
      float m0 = (vy[0] && vx[dj]) ? acc[0 + dj] : 0.f;
      float m1 = (vy[1] && vx[dj]) ? acc[5 + dj] : 0.f;
      float m2 = (vy[2] && vx[dj]) ? acc[10 + dj] : 0.f;
      float m3 = (vy[3] && vx[dj]) ? acc[15 + dj] : 0.f;
      float m4 = (vy[4] && vx[dj]) ? acc[20 + dj] : 0.f;
      rs[0][dj] = m0 + m1; rs[1][dj] = m2 + m3; rs[2][dj] = m4;
    }
  } else {
#pragma unroll
    for (int dj = 0; dj < 5; ++dj) {
      float m0 = (vy[0] && vx[dj]) ? acc[0 + dj] : 0.f;
      float m1 = (vy[1] && vx[dj]) ? acc[5 + dj] : 0.f;
      float m2 = (vy[2] && vx[dj]) ? acc[10 + dj] : 0.f;
      float m3 = (vy[3] && vx[dj]) ? acc[15 + dj] : 0.f;
      float m4 = (vy[4] && vx[dj]) ? acc[20 + dj] : 0.f;
      rs[0][dj] = m0; rs[1][dj] = m1 + m2; rs[2][dj] = m3 + m4;
    }
  }
  float cw[9];
#pragma unroll
  for (int r = 0; r < 3; ++r) {
    if (px == 0) {
      cw[r * 3 + 0] = (rs[r][0] + rs[r][1]) * inv;
      cw[r * 3 + 1] = (rs[r][2] + rs[r][3]) * inv;
      cw[r * 3 + 2] = rs[r][4] * inv;
    } else {
      cw[r * 3 + 0] = rs[r][0] * inv;
      cw[r * 3 + 1] = (rs[r][1] + rs[r][2]) * inv;
      cw[r * 3 + 2] = (rs[r][3] + rs[r][4]) * inv;
    }
  }

  // fused CARAFE from the SAME LDS patches. Local 3x3 window base = (ly,lx);
  // OOB slots are zero in LDS and have cw==0 (fold masks) -> exact.
  const int pix = y * OW + x;
  for (int c = 0; c < 19; ++c) {
    const float* p = ss + c * 144 + ly * 36 + lx;
    float a = cw[0] * p[0]  + cw[1] * p[1]  + cw[2] * p[2]
            + cw[3] * p[36] + cw[4] * p[37] + cw[5] * p[38]
            + cw[6] * p[72] + cw[7] * p[73] + cw[8] * p[74];
    outS[c * Np + pix] = a;
  }
  if (MODE == 0) {
    for (int c = 0; c < 32; ++c) {
      const float* p = sf + c * 144 + ly * 36 + lx;
      float a = cw[0] * p[0]  + cw[1] * p[1]  + cw[2] * p[2]
              + cw[3] * p[36] + cw[4] * p[37] + cw[5] * p[38]
              + cw[6] * p[72] + cw[7] * p[73] + cw[8] * p[74];
      outF[c * Np + pix] = a;
    }
  }
}

extern "C" void kernel_launch(void* const* d_in, const int* in_sizes, int n_in,
                              void* d_out, int out_size, void* d_ws, size_t ws_size,
                              hipStream_t stream) {
  (void)in_sizes; (void)n_in; (void)out_size; (void)ws_size;
  const float* feat = (const float*)d_in[0];  // [1,32,96,96]
  const float* seg  = (const float*)d_in[1];  // [1,19,96,96]
  const float* img  = (const float*)d_in[2];  // [1,3,384,384]
  const float* w0   = (const float*)d_in[3];  // [25,35,3,3]
  const float* b0   = (const float*)d_in[4];  // [25]
  const float* w1   = (const float*)d_in[5];
  const float* b1   = (const float*)d_in[6];
  float* out = (float*)d_out;                 // [1,19,384,384]

  float* ws   = (float*)d_ws;
  float* HF0  = ws;                    // 3*192*192
  float* F1   = HF0  + 3 * 192 * 192;  // 32*192*192
  float* S1   = F1   + 32 * 192 * 192; // 19*192*192
  float* W2_0 = S1   + 19 * 192 * 192; // 12800
  float* WTH0 = W2_0 + 12800;          // 675
  float* W2_1 = WTH0 + 675;            // 12800
  float* WTH1 = W2_1 + 12800;          // 675
  // ~8.0 MB of workspace

  // 1) repack both weight sets + HF0 (all from inputs; no interdeps)
  prep_kernel<<<538, 256, 0, stream>>>(w0, w1, img, W2_0, WTH0, W2_1, WTH1, HF0);

  // 2) iter-0 fused: conv+softmax+fold+carafe -> F1 (32ch), S1 (19ch)
  fused_kernel<0><<<48 * 3, 256, 0, stream>>>(
      feat, seg, img, HF0, W2_0, WTH0, b0, F1, S1, 96, 96);

  // 3) iter-1 fused: HF1 inline from img; carafe -> out (19ch only)
  fused_kernel<1><<<96 * 6, 256, 0, stream>>>(
      F1, S1, img, nullptr, W2_1, WTH1, b1, nullptr, out, 192, 192);
}